// Round 7
// baseline (159.239 us; speedup 1.0000x reference)
//
#include <hip/hip_runtime.h>
#include <cstdint>
#include <cstddef>

typedef int   v4i __attribute__((ext_vector_type(4)));
typedef float v4f __attribute__((ext_vector_type(4)));

static constexpr int NREP = 8;    // stats replica count (atomic contention spreading)

// ---------------- workspace layout (bytes) ----------------
static constexpr size_t WQ_OFF    = 0;                        // 65536 int8 weights
static constexpr size_t STATS_OFF = 65536;                    // NREP*512 int32 = 16384
static constexpr size_t PART_OFF  = STATS_OFF + NREP*512*4;   // 64 floats
static constexpr size_t BAR_OFF   = PART_OFF + 64*4;          // 1 int (grid barrier)
static constexpr size_t SBUF_OFF  = 131072 + 2048;            // 16 MiB s-values (fallback path)
static constexpr size_t WS_SBUF_NEEDED = SBUF_OFF + (size_t)65536 * 256;
static constexpr size_t WS_MIN    = BAR_OFF + 64;             // fused path needs only this

// exact round-half-even of p/1792 for |p| <= 13440 (1792 = 7*256)
__device__ __forceinline__ int rhe1792(int p) {
    unsigned u = (unsigned)(p + 17024);      // (p+896) + 9*1792, u in [3584,30464]
    unsigned v = u >> 8;                     // floor(u/256), in [14,119]
    unsigned d = (v * 147u) >> 10;           // floor(v/7), exact for v<=119
    int q = (int)d - 9;                      // round-half-up(p/1792)
    unsigned tie = (unsigned)(((u & 255u) | (v - 7u * d)) == 0u);
    q -= (int)(tie & ((unsigned)q & 1u));    // half-even: ties round to even
    return q;
}

// ---------------- k1: per-block max|w| partials + zero stats + zero barrier ----
__global__ void k_maxabs(const float* __restrict__ w, float* __restrict__ partials,
                         int* __restrict__ stats, int* __restrict__ bar) {
    __shared__ float wmax[4];
    int idx = blockIdx.x * 256 + threadIdx.x;     // 64 blocks * 256 = 16384 float4
    float4 f = ((const float4*)w)[idx];
    float m = fmaxf(fmaxf(fabsf(f.x), fabsf(f.y)), fmaxf(fabsf(f.z), fabsf(f.w)));
    #pragma unroll
    for (int s = 32; s > 0; s >>= 1) m = fmaxf(m, __shfl_xor(m, s, 64));
    if ((threadIdx.x & 63) == 0) wmax[threadIdx.x >> 6] = m;
    if (idx < NREP * 512) stats[idx] = 0;         // zero replicas
    if (idx == 0) *bar = 0;                       // zero grid barrier (ws is poisoned)
    __syncthreads();
    if (threadIdx.x == 0)
        partials[blockIdx.x] = fmaxf(fmaxf(wmax[0], wmax[1]), fmaxf(wmax[2], wmax[3]));
}

// wave-redundant reduce of the 64 partials (L2-hot) -> global max|w|
__device__ __forceinline__ float reduce_partials(const float* __restrict__ partials, int tid) {
    float p = partials[tid & 63];
    #pragma unroll
    for (int s = 32; s > 0; s >>= 1) p = fmaxf(p, __shfl_xor(p, s, 64));
    return p;
}

// ---------------- k2: quantize weights to int8 ----------------
__global__ void k_wquant(const float* __restrict__ w, const float* __restrict__ partials,
                         signed char* __restrict__ wq) {
    int idx = blockIdx.x * 256 + threadIdx.x;
    float scale = reduce_partials(partials, threadIdx.x) / 7.0f;  // scale_w (f32 div, as ref)
    float4 f = ((const float4*)w)[idx];
    int q0 = (int)rintf(fminf(fmaxf(f.x / scale, -7.f), 7.f));
    int q1 = (int)rintf(fminf(fmaxf(f.y / scale, -7.f), 7.f));
    int q2 = (int)rintf(fminf(fmaxf(f.z / scale, -7.f), 7.f));
    int q3 = (int)rintf(fminf(fmaxf(f.w / scale, -7.f), 7.f));
    ((int*)wq)[idx] = (q0 & 255) | ((q1 & 255) << 8) | ((q2 & 255) << 16) | ((q3 & 255) << 24);
}

// ---------------- k3: fused GEMM + stats, MANUAL grid barrier, BN + output ----
// 256 blocks x 1024 threads (16 waves), 256 batch rows/block, regular launch.
// Round-6 diagnosis: k_fused 63us vs ~17us traffic floor with Occupancy ~20%
// (8 waves/CU) -- every phase latency-bound on too little TLP. Fix: double
// waves at constant LDS (137.2KB, still 1 block/CU). Each wave now owns 16
// channels (wf[1][4] = 16 VGPR), per-thread demand ~100 < the 128 cap the
// compiler enforces at 16 waves/CU (rounds 1/3/4: exceeding the cap ->
// scratch spill, visible as WRITE_SIZE >> 68MB).
// s-packs in LDS across the barrier (round-5 fix). Barrier: LDS forces
// 1 block/CU, grid 256 = CU count -> co-residency guaranteed; bounded spin
// (~10ms) turns any anomaly into a wrong answer instead of a hang.
// MFMA operands swapped (A=weights, B=acts): C row = channel (quad*4+e),
// col = batch row (lr) -> phase-2 writes are float4 / 64B clusters.
__global__ __launch_bounds__(1024, 1) void k_fused(
    const float* __restrict__ x, const signed char* __restrict__ wq,
    const float* __restrict__ partials, int* __restrict__ stats,
    int* __restrict__ bar,
    const float* __restrict__ gamma, const float* __restrict__ beta,
    float* __restrict__ out)
{
    __shared__ __align__(16) signed char ldsx[256 * 272];  // 256 rows x 256 k (+16B pad/row)
    __shared__ __align__(16) unsigned slds[16 * 1024];     // s-packs: [t][tid], 64 KB
    __shared__ __align__(16) float abA[256];
    __shared__ __align__(16) float abB[256];

    const int tid  = threadIdx.x;
    const int lane = tid & 63;
    const int wv   = tid >> 6;            // 0..15
    const int obase = wv * 16;            // 16 channels per wave
    const int lr = lane & 15, quad = lane >> 4;
    const size_t rb0 = (size_t)blockIdx.x * 256;

    // ---- weight fragments (L2-hot): A row = channel, k = kt*64 + quad*16 + i ----
    v4i wf[4];
    #pragma unroll
    for (int kt = 0; kt < 4; ++kt)
        wf[kt] = *(const v4i*)(wq + (size_t)(obase + lr) * 256 + kt * 64 + quad * 16);

    // ---- stage x: issue ALL 16 float4 loads first (max in-flight), then
    //      quantize -> LDS (256 rows) ----
    const v4f* xb = (const v4f*)(x + rb0 * 256);
    {
        v4f f[16];
        #pragma unroll
        for (int j = 0; j < 16; ++j)
            f[j] = xb[j * 1024 + tid];
        #pragma unroll
        for (int j = 0; j < 16; ++j) {
            int idx = j * 1024 + tid;             // float4 flat index (0..16383)
            int row = idx >> 6, c = idx & 63;     // 64 float4 per row
            int b0 = (int)rintf(fminf(fmaxf(f[j][0], 0.f), 1.f) * 15.f);
            int b1 = (int)rintf(fminf(fmaxf(f[j][1], 0.f), 1.f) * 15.f);
            int b2 = (int)rintf(fminf(fmaxf(f[j][2], 0.f), 1.f) * 15.f);
            int b3 = (int)rintf(fminf(fmaxf(f[j][3], 0.f), 1.f) * 15.f);
            *(int*)(ldsx + row * 272 + c * 4) = b0 | (b1 << 8) | (b2 << 16) | (b3 << 24);
        }
    }
    __syncthreads();   // the ONLY block barrier in phase 1

    int ssum[4] = {};
    int ssq [4] = {};

    #pragma unroll
    for (int t = 0; t < 16; ++t) {
        v4i a[4];
        #pragma unroll
        for (int kt = 0; kt < 4; ++kt)
            a[kt] = *(const v4i*)(ldsx + (t * 16 + lr) * 272 + kt * 64 + quad * 16);
        v4i acc0 = {0, 0, 0, 0}, acc1 = {0, 0, 0, 0};
        // D[r=channel][c=batchrow]: A = weights, B = acts (swapped)
        acc0 = __builtin_amdgcn_mfma_i32_16x16x64_i8(wf[0], a[0], acc0, 0, 0, 0);
        acc0 = __builtin_amdgcn_mfma_i32_16x16x64_i8(wf[1], a[1], acc0, 0, 0, 0);
        acc1 = __builtin_amdgcn_mfma_i32_16x16x64_i8(wf[2], a[2], acc1, 0, 0, 0);
        acc1 = __builtin_amdgcn_mfma_i32_16x16x64_i8(wf[3], a[3], acc1, 0, 0, 0);
        unsigned pack = 0;
        #pragma unroll
        for (int e = 0; e < 4; ++e) {
            int s = rhe1792(acc0[e]) + rhe1792(acc1[e]);   // exact, in [-16,16]
            ssum[e] += s;
            ssq [e] += s * s;
            pack |= (unsigned)(s & 255) << (8 * e);
        }
        // conflict-free: consecutive tid -> consecutive dwords; own-thread
        // readback in phase 2 (LDS persists across the grid barrier)
        slds[t * 1024 + tid] = pack;
    }

    // ---- per-channel stats: reduce across the 16 lr-lanes, atomics to replicas ----
    {
        int* st = stats + (blockIdx.x & (NREP - 1)) * 512;
        #pragma unroll
        for (int e = 0; e < 4; ++e) {
            int v = ssum[e], u = ssq[e];
            v += __shfl_xor(v, 1, 64); v += __shfl_xor(v, 2, 64);
            v += __shfl_xor(v, 4, 64); v += __shfl_xor(v, 8, 64);
            u += __shfl_xor(u, 1, 64); u += __shfl_xor(u, 2, 64);
            u += __shfl_xor(u, 4, 64); u += __shfl_xor(u, 8, 64);
            if (lr == 0) {
                int ch = obase + quad * 4 + e;
                atomicAdd(&st[ch], v);
                atomicAdd(&st[256 + ch], u);
            }
        }
    }

    // ---- manual grid barrier (all 256 blocks co-resident: 1 block/CU, 256 CUs) ----
    __syncthreads();   // drains this block's stats atomics (vmcnt(0) before s_barrier)
    if (tid == 0) {
        __threadfence();                         // release stats before arrival
        atomicAdd(bar, 1);                       // device-scope arrival
        int it = 0;
        while (__hip_atomic_load(bar, __ATOMIC_ACQUIRE, __HIP_MEMORY_SCOPE_AGENT) < 256) {
            __builtin_amdgcn_s_sleep(2);
            if (++it > 200000) break;            // ~10ms safety valve: wrong > hung
        }
    }
    __syncthreads();   // all threads see barrier passed

    // ---- BN affine (one channel per thread, waves 0-3), exact integer stats ----
    if (tid < 256) {
        const int o = tid;
        int s = 0, q = 0;
        #pragma unroll
        for (int rr = 0; rr < NREP; ++rr) {
            s += __hip_atomic_load(&stats[rr * 512 + o],       __ATOMIC_RELAXED, __HIP_MEMORY_SCOPE_AGENT);
            q += __hip_atomic_load(&stats[rr * 512 + 256 + o], __ATOMIC_RELAXED, __HIP_MEMORY_SCOPE_AGENT);
        }
        float scale_w = reduce_partials(partials, o) / 7.0f;
        float t = scale_w / 15.0f;                 // ref: scale_w / qmax_a in f32
        double Cs = 1792.0 * (double)t;            // acc = s * Cs
        const double N = 65536.0;
        double mean_s = (double)s / N;
        double var_s  = (double)q / N - mean_s * mean_s;
        double var    = Cs * Cs * var_s;
        double inv    = 1.0 / sqrt(var + 1e-5);
        double A = Cs * inv * (double)gamma[o];
        double B = (double)beta[o] - Cs * mean_s * inv * (double)gamma[o];
        abA[o] = (float)A;
        abB[o] = (float)B;
    }
    __syncthreads();

    // ---- epilogue from slds: float4 per t, 64B clusters per row ----
    const float inv15 = 0.066666666666666666f;
    const int ch0 = obase + quad * 4;
    v4f A4 = *(const v4f*)&abA[ch0];     // loop-invariant, hoisted (broadcast reads)
    v4f B4 = *(const v4f*)&abB[ch0];
    #pragma unroll
    for (int t = 0; t < 16; ++t) {
        unsigned pk = slds[t * 1024 + tid];
        v4f o4;
        #pragma unroll
        for (int e = 0; e < 4; ++e) {
            float v = (float)((int)(pk << (24 - 8 * e)) >> 24);
            o4[e] = rintf(fminf(fmaxf(v * A4[e] + B4[e], 0.f), 1.f) * 15.f) * inv15;
        }
        const size_t grow = rb0 + (size_t)t * 16 + lr;
        __builtin_nontemporal_store(o4, (v4f*)out + grow * 64 + (ch0 >> 2));
    }
}

// =================== fallback path (old proven 2-kernel pipeline) ===================
template <typename ST>
__global__ __launch_bounds__(512, 4) void k_gemm(
    const float* __restrict__ x, const signed char* __restrict__ wq,
    ST* __restrict__ sbuf, int* __restrict__ stats)
{
    __shared__ __align__(16) signed char ldsx[64 * 272];
    const int tid  = threadIdx.x;
    const int lane = tid & 63;
    const int wv   = tid >> 6;
    const int obase = wv * 32;
    const int lr = lane & 15, quad = lane >> 4;
    const size_t rb0 = (size_t)blockIdx.x * 64;

    v4f f[8];
    const v4f* xb = (const v4f*)(x + rb0 * 256);
    #pragma unroll
    for (int j = 0; j < 8; ++j)
        f[j] = xb[j * 512 + tid];

    v4i wf[2][4];
    #pragma unroll
    for (int ot = 0; ot < 2; ++ot)
        #pragma unroll
        for (int kt = 0; kt < 4; ++kt)
            wf[ot][kt] = *(const v4i*)(wq + (size_t)(obase + ot * 16 + lr) * 256 + kt * 64 + quad * 16);

    #pragma unroll
    for (int j = 0; j < 8; ++j) {
        int idx = j * 512 + tid;
        int row = idx >> 6, c = idx & 63;
        int b0 = (int)rintf(fminf(fmaxf(f[j][0], 0.f), 1.f) * 15.f);
        int b1 = (int)rintf(fminf(fmaxf(f[j][1], 0.f), 1.f) * 15.f);
        int b2 = (int)rintf(fminf(fmaxf(f[j][2], 0.f), 1.f) * 15.f);
        int b3 = (int)rintf(fminf(fmaxf(f[j][3], 0.f), 1.f) * 15.f);
        *(int*)(ldsx + row * 272 + c * 4) = b0 | (b1 << 8) | (b2 << 16) | (b3 << 24);
    }
    __syncthreads();

    int ssum[2] = {0, 0};
    int ssq[2]  = {0, 0};

    #pragma unroll
    for (int t = 0; t < 4; ++t) {
        v4i a[4];
        #pragma unroll
        for (int kt = 0; kt < 4; ++kt)
            a[kt] = *(const v4i*)(ldsx + (t * 16 + lr) * 272 + kt * 64 + quad * 16);
        #pragma unroll
        for (int ot = 0; ot < 2; ++ot) {
            v4i acc0 = {0, 0, 0, 0}, acc1 = {0, 0, 0, 0};
            acc0 = __builtin_amdgcn_mfma_i32_16x16x64_i8(a[0], wf[ot][0], acc0, 0, 0, 0);
            acc0 = __builtin_amdgcn_mfma_i32_16x16x64_i8(a[1], wf[ot][1], acc0, 0, 0, 0);
            acc1 = __builtin_amdgcn_mfma_i32_16x16x64_i8(a[2], wf[ot][2], acc1, 0, 0, 0);
            acc1 = __builtin_amdgcn_mfma_i32_16x16x64_i8(a[3], wf[ot][3], acc1, 0, 0, 0);
            const int ocol = obase + ot * 16 + lr;
            if constexpr (sizeof(ST) == 1) {
                unsigned pack = 0;
                #pragma unroll
                for (int e = 0; e < 4; ++e) {
                    int s = rhe1792(acc0[e]) + rhe1792(acc1[e]);
                    ssum[ot] += s;
                    ssq[ot]  += s * s;
                    pack |= (unsigned)(s & 255) << (8 * e);
                }
                const size_t rg = (size_t)blockIdx.x * 16 + t * 4 + quad;
                ((unsigned*)sbuf)[rg * 256 + ocol] = pack;
            } else {
                ST* sp = sbuf + (rb0 + (size_t)t * 16 + quad * 4) * 256 + ocol;
                #pragma unroll
                for (int e = 0; e < 4; ++e) {
                    int s = rhe1792(acc0[e]) + rhe1792(acc1[e]);
                    ssum[ot] += s;
                    ssq[ot]  += s * s;
                    sp[(size_t)e * 256] = (ST)s;
                }
            }
        }
    }
    int* st = stats + (blockIdx.x & (NREP - 1)) * 512;
    #pragma unroll
    for (int ot = 0; ot < 2; ++ot) {
        int v = ssum[ot], u = ssq[ot];
        v += __shfl_xor(v, 16, 64); v += __shfl_xor(v, 32, 64);
        u += __shfl_xor(u, 16, 64); u += __shfl_xor(u, 32, 64);
        if (quad == 0) {
            atomicAdd(&st[obase + ot * 16 + lr], v);
            atomicAdd(&st[256 + obase + ot * 16 + lr], u);
        }
    }
}

template <typename LT>
__global__ __launch_bounds__(256) void k_out(const LT* sbuf, const int* __restrict__ stats,
                                             const float* __restrict__ partials,
                                             const float* __restrict__ gamma,
                                             const float* __restrict__ beta,
                                             float* out)
{
    __shared__ float2 ab[256];
    const int tid = threadIdx.x;
    {
        int o = tid;
        int s = 0, q = 0;
        #pragma unroll
        for (int rr = 0; rr < NREP; ++rr) {
            s += stats[rr * 512 + o];
            q += stats[rr * 512 + 256 + o];
        }
        float scale_w = reduce_partials(partials, o) / 7.0f;
        float t = scale_w / 15.0f;
        double Cs = 1792.0 * (double)t;
        const double N = 65536.0;
        double mean_s = (double)s / N;
        double var_s  = (double)q / N - mean_s * mean_s;
        double var    = Cs * Cs * var_s;
        double inv    = 1.0 / sqrt(var + 1e-5);
        double A = Cs * inv * (double)gamma[o];
        double B = (double)beta[o] - Cs * mean_s * inv * (double)gamma[o];
        ab[o] = make_float2((float)A, (float)B);
    }
    __syncthreads();

    const int b = blockIdx.x;
    const int d = ((b & 7) << 2) | ((b >> 3) & 3) | (b & ~31);
    const int ci = tid & 63;
    const int c0 = ci * 4;
    const float2 p0 = ab[c0], p1 = ab[c0 + 1], p2 = ab[c0 + 2], p3 = ab[c0 + 3];
    const float inv15 = 0.066666666666666666f;

    if constexpr (sizeof(LT) == 1) {
        const int rg = d * 4 + (tid >> 6);
        v4i V = ((const v4i*)sbuf)[(size_t)rg * 64 + ci];
        #pragma unroll
        for (int j = 0; j < 4; ++j) {
            float v0 = (float)((V[0] << (24 - 8 * j)) >> 24);
            float v1 = (float)((V[1] << (24 - 8 * j)) >> 24);
            float v2 = (float)((V[2] << (24 - 8 * j)) >> 24);
            float v3 = (float)((V[3] << (24 - 8 * j)) >> 24);
            float y0 = rintf(fminf(fmaxf(v0 * p0.x + p0.y, 0.f), 1.f) * 15.f);
            float y1 = rintf(fminf(fmaxf(v1 * p1.x + p1.y, 0.f), 1.f) * 15.f);
            float y2 = rintf(fminf(fmaxf(v2 * p2.x + p2.y, 0.f), 1.f) * 15.f);
            float y3 = rintf(fminf(fmaxf(v3 * p3.x + p3.y, 0.f), 1.f) * 15.f);
            v4f o = { y0 * inv15, y1 * inv15, y2 * inv15, y3 * inv15 };
            __builtin_nontemporal_store(o, (v4f*)out + (size_t)(4 * rg + j) * 64 + ci);
        }
    } else {
        const size_t base = (size_t)d * 1024 + tid;
        #pragma unroll
        for (int j = 0; j < 4; ++j) {
            const size_t F4 = base + (size_t)j * 256;
            v4f fl = ((const v4f*)sbuf)[F4];
            const int oo = (tid * 4) & 255;
            float2 q0 = ab[oo], q1 = ab[oo + 1], q2 = ab[oo + 2], q3 = ab[oo + 3];
            float y0 = rintf(fminf(fmaxf(fl[0] * q0.x + q0.y, 0.f), 1.f) * 15.f);
            float y1 = rintf(fminf(fmaxf(fl[1] * q1.x + q1.y, 0.f), 1.f) * 15.f);
            float y2 = rintf(fminf(fmaxf(fl[2] * q2.x + q2.y, 0.f), 1.f) * 15.f);
            float y3 = rintf(fminf(fmaxf(fl[3] * q3.x + q3.y, 0.f), 1.f) * 15.f);
            v4f o = { y0 * inv15, y1 * inv15, y2 * inv15, y3 * inv15 };
            __builtin_nontemporal_store(o, (v4f*)out + F4);
        }
    }
}

// ---------------- launch ----------------
extern "C" void kernel_launch(void* const* d_in, const int* in_sizes, int n_in,
                              void* d_out, int out_size, void* d_ws, size_t ws_size,
                              hipStream_t stream)
{
    const float* x     = (const float*)d_in[0];
    const float* w     = (const float*)d_in[1];
    const float* gamma = (const float*)d_in[2];
    const float* beta  = (const float*)d_in[3];
    float* out = (float*)d_out;
    char* ws = (char*)d_ws;

    signed char* wq       = (signed char*)(ws + WQ_OFF);
    int*         stats    = (int*)(ws + STATS_OFF);
    float*       partials = (float*)(ws + PART_OFF);
    int*         bar      = (int*)(ws + BAR_OFF);

    k_maxabs<<<dim3(64), dim3(256), 0, stream>>>(w, partials, stats, bar);
    k_wquant<<<dim3(64), dim3(256), 0, stream>>>(w, partials, wq);

    if (ws_size >= WS_MIN) {
        k_fused<<<dim3(256), dim3(1024), 0, stream>>>(x, wq, partials, stats, bar,
                                                      gamma, beta, out);
    } else {
        // fallback: old proven 4-kernel pipeline
        if (ws_size >= WS_SBUF_NEEDED) {
            signed char* sbuf = (signed char*)(ws + SBUF_OFF);
            k_gemm<signed char><<<dim3(1024), dim3(512), 0, stream>>>(x, wq, sbuf, stats);
            k_out<signed char><<<dim3(4096), dim3(256), 0, stream>>>(sbuf, stats, partials,
                                                                     gamma, beta, out);
        } else {
            k_gemm<float><<<dim3(1024), dim3(512), 0, stream>>>(x, wq, out, stats);
            k_out<float><<<dim3(4096), dim3(256), 0, stream>>>(out, stats, partials,
                                                               gamma, beta, out);
        }
    }
}

// Round 8
// 155.177 us; speedup vs baseline: 1.0262x; 1.0262x over previous
//
#include <hip/hip_runtime.h>
#include <cstdint>
#include <cstddef>

typedef int   v4i __attribute__((ext_vector_type(4)));
typedef float v4f __attribute__((ext_vector_type(4)));

static constexpr int NREP = 8;    // stats replica count (atomic contention spreading)

// ---------------- workspace layout (bytes) ----------------
static constexpr size_t WQ_OFF    = 0;                        // 65536 int8 weights
static constexpr size_t STATS_OFF = 65536;                    // NREP*512 int32 = 16384
static constexpr size_t PART_OFF  = STATS_OFF + NREP*512*4;   // 64 floats
static constexpr size_t BAR_OFF   = PART_OFF + 64*4;          // 1 int (grid barrier)
static constexpr size_t SBUF_OFF  = 131072 + 2048;            // 16 MiB s-values (fallback path)
static constexpr size_t WS_SBUF_NEEDED = SBUF_OFF + (size_t)65536 * 256;
static constexpr size_t WS_MIN    = BAR_OFF + 64;             // fused path needs only this

// exact round-half-even of p/1792 for |p| <= 13440 (1792 = 7*256)
__device__ __forceinline__ int rhe1792(int p) {
    unsigned u = (unsigned)(p + 17024);      // (p+896) + 9*1792, u in [3584,30464]
    unsigned v = u >> 8;                     // floor(u/256), in [14,119]
    unsigned d = (v * 147u) >> 10;           // floor(v/7), exact for v<=119
    int q = (int)d - 9;                      // round-half-up(p/1792)
    unsigned tie = (unsigned)(((u & 255u) | (v - 7u * d)) == 0u);
    q -= (int)(tie & ((unsigned)q & 1u));    // half-even: ties round to even
    return q;
}

// ---------------- k1: per-block max|w| partials + zero stats + zero barrier ----
__global__ void k_maxabs(const float* __restrict__ w, float* __restrict__ partials,
                         int* __restrict__ stats, int* __restrict__ bar) {
    __shared__ float wmax[4];
    int idx = blockIdx.x * 256 + threadIdx.x;     // 64 blocks * 256 = 16384 float4
    float4 f = ((const float4*)w)[idx];
    float m = fmaxf(fmaxf(fabsf(f.x), fabsf(f.y)), fmaxf(fabsf(f.z), fabsf(f.w)));
    #pragma unroll
    for (int s = 32; s > 0; s >>= 1) m = fmaxf(m, __shfl_xor(m, s, 64));
    if ((threadIdx.x & 63) == 0) wmax[threadIdx.x >> 6] = m;
    if (idx < NREP * 512) stats[idx] = 0;         // zero replicas
    if (idx == 0) *bar = 0;                       // zero grid barrier (ws is poisoned)
    __syncthreads();
    if (threadIdx.x == 0)
        partials[blockIdx.x] = fmaxf(fmaxf(wmax[0], wmax[1]), fmaxf(wmax[2], wmax[3]));
}

// wave-redundant reduce of the 64 partials (L2-hot) -> global max|w|
__device__ __forceinline__ float reduce_partials(const float* __restrict__ partials, int tid) {
    float p = partials[tid & 63];
    #pragma unroll
    for (int s = 32; s > 0; s >>= 1) p = fmaxf(p, __shfl_xor(p, s, 64));
    return p;
}

// ---------------- k2: quantize weights to int8 ----------------
__global__ void k_wquant(const float* __restrict__ w, const float* __restrict__ partials,
                         signed char* __restrict__ wq) {
    int idx = blockIdx.x * 256 + threadIdx.x;
    float scale = reduce_partials(partials, threadIdx.x) / 7.0f;  // scale_w (f32 div, as ref)
    float4 f = ((const float4*)w)[idx];
    int q0 = (int)rintf(fminf(fmaxf(f.x / scale, -7.f), 7.f));
    int q1 = (int)rintf(fminf(fmaxf(f.y / scale, -7.f), 7.f));
    int q2 = (int)rintf(fminf(fmaxf(f.z / scale, -7.f), 7.f));
    int q3 = (int)rintf(fminf(fmaxf(f.w / scale, -7.f), 7.f));
    ((int*)wq)[idx] = (q0 & 255) | ((q1 & 255) << 8) | ((q2 & 255) << 16) | ((q3 & 255) << 24);
}

// ---------------- k3: fused GEMM + stats, MANUAL grid barrier, BN + output ----
// 256 blocks x 1024 threads (16 waves), 256 batch rows/block, regular launch.
// Register-cap ledger (rounds 1/3/4/5/7): the allocator's occupancy heuristic
// picked 64/128/128/88/56 VGPR with no consistent link to __launch_bounds__;
// round 7's 56-cap + f[16] staging (64 regs) = 28MB scratch spill (WRITE 95MB).
// Fix: PIN the budget with amdgpu_waves_per_eu(4,4) -> 4 waves/EU, per-EU file
// 512 regs (m69 halving points) -> exactly 128 VGPR; stage in 2 passes of 8
// float4 (f[8]=32 regs, peak demand ~90 < 128) -> no spill by construction.
// Occupancy gain of 16 waves (round 7: 20%->38%, HBM 1.65->1.83 TB/s) kept.
// s-packs in LDS across the barrier (round-5 fix). Barrier: LDS 137KB forces
// 1 block/CU, grid 256 = CU count -> co-residency guaranteed; bounded spin
// (~10ms) turns any anomaly into a wrong answer instead of a hang.
// MFMA operands swapped (A=weights, B=acts): C row = channel (quad*4+e),
// col = batch row (lr) -> phase-2 writes are float4 / 64B clusters.
__global__
__attribute__((amdgpu_flat_work_group_size(1024, 1024)))
__attribute__((amdgpu_waves_per_eu(4, 4)))
void k_fused(
    const float* __restrict__ x, const signed char* __restrict__ wq,
    const float* __restrict__ partials, int* __restrict__ stats,
    int* __restrict__ bar,
    const float* __restrict__ gamma, const float* __restrict__ beta,
    float* __restrict__ out)
{
    __shared__ __align__(16) signed char ldsx[256 * 272];  // 256 rows x 256 k (+16B pad/row)
    __shared__ __align__(16) unsigned slds[16 * 1024];     // s-packs: [t][tid], 64 KB
    __shared__ __align__(16) float abA[256];
    __shared__ __align__(16) float abB[256];

    const int tid  = threadIdx.x;
    const int lane = tid & 63;
    const int wv   = tid >> 6;            // 0..15
    const int obase = wv * 16;            // 16 channels per wave
    const int lr = lane & 15, quad = lane >> 4;
    const size_t rb0 = (size_t)blockIdx.x * 256;

    // ---- weight fragments (L2-hot): A row = channel, k = kt*64 + quad*16 + i ----
    v4i wf[4];
    #pragma unroll
    for (int kt = 0; kt < 4; ++kt)
        wf[kt] = *(const v4i*)(wq + (size_t)(obase + lr) * 256 + kt * 64 + quad * 16);

    // ---- stage x -> quantize -> LDS, 2 passes of 8 float4/thread (256 rows) ----
    const v4f* xb = (const v4f*)(x + rb0 * 256);
    #pragma unroll
    for (int p = 0; p < 2; ++p) {
        v4f f[8];
        #pragma unroll
        for (int j = 0; j < 8; ++j)
            f[j] = xb[p * 8192 + j * 1024 + tid];
        #pragma unroll
        for (int j = 0; j < 8; ++j) {
            int idx = p * 8192 + j * 1024 + tid;  // float4 flat index (0..16383)
            int row = idx >> 6, c = idx & 63;     // 64 float4 per row
            int b0 = (int)rintf(fminf(fmaxf(f[j][0], 0.f), 1.f) * 15.f);
            int b1 = (int)rintf(fminf(fmaxf(f[j][1], 0.f), 1.f) * 15.f);
            int b2 = (int)rintf(fminf(fmaxf(f[j][2], 0.f), 1.f) * 15.f);
            int b3 = (int)rintf(fminf(fmaxf(f[j][3], 0.f), 1.f) * 15.f);
            *(int*)(ldsx + row * 272 + c * 4) = b0 | (b1 << 8) | (b2 << 16) | (b3 << 24);
        }
    }
    __syncthreads();   // the ONLY block barrier in phase 1

    int ssum[4] = {};
    int ssq [4] = {};

    #pragma unroll
    for (int t = 0; t < 16; ++t) {
        v4i a[4];
        #pragma unroll
        for (int kt = 0; kt < 4; ++kt)
            a[kt] = *(const v4i*)(ldsx + (t * 16 + lr) * 272 + kt * 64 + quad * 16);
        v4i acc0 = {0, 0, 0, 0}, acc1 = {0, 0, 0, 0};
        // D[r=channel][c=batchrow]: A = weights, B = acts (swapped)
        acc0 = __builtin_amdgcn_mfma_i32_16x16x64_i8(wf[0], a[0], acc0, 0, 0, 0);
        acc0 = __builtin_amdgcn_mfma_i32_16x16x64_i8(wf[1], a[1], acc0, 0, 0, 0);
        acc1 = __builtin_amdgcn_mfma_i32_16x16x64_i8(wf[2], a[2], acc1, 0, 0, 0);
        acc1 = __builtin_amdgcn_mfma_i32_16x16x64_i8(wf[3], a[3], acc1, 0, 0, 0);
        unsigned pack = 0;
        #pragma unroll
        for (int e = 0; e < 4; ++e) {
            int s = rhe1792(acc0[e]) + rhe1792(acc1[e]);   // exact, in [-16,16]
            ssum[e] += s;
            ssq [e] += s * s;
            pack |= (unsigned)(s & 255) << (8 * e);
        }
        // conflict-free: consecutive tid -> consecutive dwords; own-thread
        // readback in phase 2 (LDS persists across the grid barrier)
        slds[t * 1024 + tid] = pack;
    }

    // ---- per-channel stats: reduce across the 16 lr-lanes, atomics to replicas ----
    {
        int* st = stats + (blockIdx.x & (NREP - 1)) * 512;
        #pragma unroll
        for (int e = 0; e < 4; ++e) {
            int v = ssum[e], u = ssq[e];
            v += __shfl_xor(v, 1, 64); v += __shfl_xor(v, 2, 64);
            v += __shfl_xor(v, 4, 64); v += __shfl_xor(v, 8, 64);
            u += __shfl_xor(u, 1, 64); u += __shfl_xor(u, 2, 64);
            u += __shfl_xor(u, 4, 64); u += __shfl_xor(u, 8, 64);
            if (lr == 0) {
                int ch = obase + quad * 4 + e;
                atomicAdd(&st[ch], v);
                atomicAdd(&st[256 + ch], u);
            }
        }
    }

    // ---- manual grid barrier (all 256 blocks co-resident: 1 block/CU, 256 CUs) ----
    __syncthreads();   // drains this block's stats atomics (vmcnt(0) before s_barrier)
    if (tid == 0) {
        __threadfence();                         // release stats before arrival
        atomicAdd(bar, 1);                       // device-scope arrival
        int it = 0;
        while (__hip_atomic_load(bar, __ATOMIC_ACQUIRE, __HIP_MEMORY_SCOPE_AGENT) < 256) {
            __builtin_amdgcn_s_sleep(2);
            if (++it > 200000) break;            // ~10ms safety valve: wrong > hung
        }
    }
    __syncthreads();   // all threads see barrier passed

    // ---- BN affine (one channel per thread, first 256 threads), exact stats ----
    if (tid < 256) {
        const int o = tid;
        int s = 0, q = 0;
        #pragma unroll
        for (int rr = 0; rr < NREP; ++rr) {
            s += __hip_atomic_load(&stats[rr * 512 + o],       __ATOMIC_RELAXED, __HIP_MEMORY_SCOPE_AGENT);
            q += __hip_atomic_load(&stats[rr * 512 + 256 + o], __ATOMIC_RELAXED, __HIP_MEMORY_SCOPE_AGENT);
        }
        float scale_w = reduce_partials(partials, o) / 7.0f;
        float t = scale_w / 15.0f;                 // ref: scale_w / qmax_a in f32
        double Cs = 1792.0 * (double)t;            // acc = s * Cs
        const double N = 65536.0;
        double mean_s = (double)s / N;
        double var_s  = (double)q / N - mean_s * mean_s;
        double var    = Cs * Cs * var_s;
        double inv    = 1.0 / sqrt(var + 1e-5);
        double A = Cs * inv * (double)gamma[o];
        double B = (double)beta[o] - Cs * mean_s * inv * (double)gamma[o];
        abA[o] = (float)A;
        abB[o] = (float)B;
    }
    __syncthreads();

    // ---- epilogue from slds: float4 per t, 64B clusters per row ----
    const float inv15 = 0.066666666666666666f;
    const int ch0 = obase + quad * 4;
    v4f A4 = *(const v4f*)&abA[ch0];     // loop-invariant, hoisted (broadcast reads)
    v4f B4 = *(const v4f*)&abB[ch0];
    #pragma unroll
    for (int t = 0; t < 16; ++t) {
        unsigned pk = slds[t * 1024 + tid];
        v4f o4;
        #pragma unroll
        for (int e = 0; e < 4; ++e) {
            float v = (float)((int)(pk << (24 - 8 * e)) >> 24);
            o4[e] = rintf(fminf(fmaxf(v * A4[e] + B4[e], 0.f), 1.f) * 15.f) * inv15;
        }
        const size_t grow = rb0 + (size_t)t * 16 + lr;
        __builtin_nontemporal_store(o4, (v4f*)out + grow * 64 + (ch0 >> 2));
    }
}

// =================== fallback path (old proven 2-kernel pipeline) ===================
template <typename ST>
__global__ __launch_bounds__(512, 4) void k_gemm(
    const float* __restrict__ x, const signed char* __restrict__ wq,
    ST* __restrict__ sbuf, int* __restrict__ stats)
{
    __shared__ __align__(16) signed char ldsx[64 * 272];
    const int tid  = threadIdx.x;
    const int lane = tid & 63;
    const int wv   = tid >> 6;
    const int obase = wv * 32;
    const int lr = lane & 15, quad = lane >> 4;
    const size_t rb0 = (size_t)blockIdx.x * 64;

    v4f f[8];
    const v4f* xb = (const v4f*)(x + rb0 * 256);
    #pragma unroll
    for (int j = 0; j < 8; ++j)
        f[j] = xb[j * 512 + tid];

    v4i wf[2][4];
    #pragma unroll
    for (int ot = 0; ot < 2; ++ot)
        #pragma unroll
        for (int kt = 0; kt < 4; ++kt)
            wf[ot][kt] = *(const v4i*)(wq + (size_t)(obase + ot * 16 + lr) * 256 + kt * 64 + quad * 16);

    #pragma unroll
    for (int j = 0; j < 8; ++j) {
        int idx = j * 512 + tid;
        int row = idx >> 6, c = idx & 63;
        int b0 = (int)rintf(fminf(fmaxf(f[j][0], 0.f), 1.f) * 15.f);
        int b1 = (int)rintf(fminf(fmaxf(f[j][1], 0.f), 1.f) * 15.f);
        int b2 = (int)rintf(fminf(fmaxf(f[j][2], 0.f), 1.f) * 15.f);
        int b3 = (int)rintf(fminf(fmaxf(f[j][3], 0.f), 1.f) * 15.f);
        *(int*)(ldsx + row * 272 + c * 4) = b0 | (b1 << 8) | (b2 << 16) | (b3 << 24);
    }
    __syncthreads();

    int ssum[2] = {0, 0};
    int ssq[2]  = {0, 0};

    #pragma unroll
    for (int t = 0; t < 4; ++t) {
        v4i a[4];
        #pragma unroll
        for (int kt = 0; kt < 4; ++kt)
            a[kt] = *(const v4i*)(ldsx + (t * 16 + lr) * 272 + kt * 64 + quad * 16);
        #pragma unroll
        for (int ot = 0; ot < 2; ++ot) {
            v4i acc0 = {0, 0, 0, 0}, acc1 = {0, 0, 0, 0};
            acc0 = __builtin_amdgcn_mfma_i32_16x16x64_i8(a[0], wf[ot][0], acc0, 0, 0, 0);
            acc0 = __builtin_amdgcn_mfma_i32_16x16x64_i8(a[1], wf[ot][1], acc0, 0, 0, 0);
            acc1 = __builtin_amdgcn_mfma_i32_16x16x64_i8(a[2], wf[ot][2], acc1, 0, 0, 0);
            acc1 = __builtin_amdgcn_mfma_i32_16x16x64_i8(a[3], wf[ot][3], acc1, 0, 0, 0);
            const int ocol = obase + ot * 16 + lr;
            if constexpr (sizeof(ST) == 1) {
                unsigned pack = 0;
                #pragma unroll
                for (int e = 0; e < 4; ++e) {
                    int s = rhe1792(acc0[e]) + rhe1792(acc1[e]);
                    ssum[ot] += s;
                    ssq[ot]  += s * s;
                    pack |= (unsigned)(s & 255) << (8 * e);
                }
                const size_t rg = (size_t)blockIdx.x * 16 + t * 4 + quad;
                ((unsigned*)sbuf)[rg * 256 + ocol] = pack;
            } else {
                ST* sp = sbuf + (rb0 + (size_t)t * 16 + quad * 4) * 256 + ocol;
                #pragma unroll
                for (int e = 0; e < 4; ++e) {
                    int s = rhe1792(acc0[e]) + rhe1792(acc1[e]);
                    ssum[ot] += s;
                    ssq[ot]  += s * s;
                    sp[(size_t)e * 256] = (ST)s;
                }
            }
        }
    }
    int* st = stats + (blockIdx.x & (NREP - 1)) * 512;
    #pragma unroll
    for (int ot = 0; ot < 2; ++ot) {
        int v = ssum[ot], u = ssq[ot];
        v += __shfl_xor(v, 16, 64); v += __shfl_xor(v, 32, 64);
        u += __shfl_xor(u, 16, 64); u += __shfl_xor(u, 32, 64);
        if (quad == 0) {
            atomicAdd(&st[obase + ot * 16 + lr], v);
            atomicAdd(&st[256 + obase + ot * 16 + lr], u);
        }
    }
}

template <typename LT>
__global__ __launch_bounds__(256) void k_out(const LT* sbuf, const int* __restrict__ stats,
                                             const float* __restrict__ partials,
                                             const float* __restrict__ gamma,
                                             const float* __restrict__ beta,
                                             float* out)
{
    __shared__ float2 ab[256];
    const int tid = threadIdx.x;
    {
        int o = tid;
        int s = 0, q = 0;
        #pragma unroll
        for (int rr = 0; rr < NREP; ++rr) {
            s += stats[rr * 512 + o];
            q += stats[rr * 512 + 256 + o];
        }
        float scale_w = reduce_partials(partials, o) / 7.0f;
        float t = scale_w / 15.0f;
        double Cs = 1792.0 * (double)t;
        const double N = 65536.0;
        double mean_s = (double)s / N;
        double var_s  = (double)q / N - mean_s * mean_s;
        double var    = Cs * Cs * var_s;
        double inv    = 1.0 / sqrt(var + 1e-5);
        double A = Cs * inv * (double)gamma[o];
        double B = (double)beta[o] - Cs * mean_s * inv * (double)gamma[o];
        ab[o] = make_float2((float)A, (float)B);
    }
    __syncthreads();

    const int b = blockIdx.x;
    const int d = ((b & 7) << 2) | ((b >> 3) & 3) | (b & ~31);
    const int ci = tid & 63;
    const int c0 = ci * 4;
    const float2 p0 = ab[c0], p1 = ab[c0 + 1], p2 = ab[c0 + 2], p3 = ab[c0 + 3];
    const float inv15 = 0.066666666666666666f;

    if constexpr (sizeof(LT) == 1) {
        const int rg = d * 4 + (tid >> 6);
        v4i V = ((const v4i*)sbuf)[(size_t)rg * 64 + ci];
        #pragma unroll
        for (int j = 0; j < 4; ++j) {
            float v0 = (float)((V[0] << (24 - 8 * j)) >> 24);
            float v1 = (float)((V[1] << (24 - 8 * j)) >> 24);
            float v2 = (float)((V[2] << (24 - 8 * j)) >> 24);
            float v3 = (float)((V[3] << (24 - 8 * j)) >> 24);
            float y0 = rintf(fminf(fmaxf(v0 * p0.x + p0.y, 0.f), 1.f) * 15.f);
            float y1 = rintf(fminf(fmaxf(v1 * p1.x + p1.y, 0.f), 1.f) * 15.f);
            float y2 = rintf(fminf(fmaxf(v2 * p2.x + p2.y, 0.f), 1.f) * 15.f);
            float y3 = rintf(fminf(fmaxf(v3 * p3.x + p3.y, 0.f), 1.f) * 15.f);
            v4f o = { y0 * inv15, y1 * inv15, y2 * inv15, y3 * inv15 };
            __builtin_nontemporal_store(o, (v4f*)out + (size_t)(4 * rg + j) * 64 + ci);
        }
    } else {
        const size_t base = (size_t)d * 1024 + tid;
        #pragma unroll
        for (int j = 0; j < 4; ++j) {
            const size_t F4 = base + (size_t)j * 256;
            v4f fl = ((const v4f*)sbuf)[F4];
            const int oo = (tid * 4) & 255;
            float2 q0 = ab[oo], q1 = ab[oo + 1], q2 = ab[oo + 2], q3 = ab[oo + 3];
            float y0 = rintf(fminf(fmaxf(fl[0] * q0.x + q0.y, 0.f), 1.f) * 15.f);
            float y1 = rintf(fminf(fmaxf(fl[1] * q1.x + q1.y, 0.f), 1.f) * 15.f);
            float y2 = rintf(fminf(fmaxf(fl[2] * q2.x + q2.y, 0.f), 1.f) * 15.f);
            float y3 = rintf(fminf(fmaxf(fl[3] * q3.x + q3.y, 0.f), 1.f) * 15.f);
            v4f o = { y0 * inv15, y1 * inv15, y2 * inv15, y3 * inv15 };
            __builtin_nontemporal_store(o, (v4f*)out + F4);
        }
    }
}

// ---------------- launch ----------------
extern "C" void kernel_launch(void* const* d_in, const int* in_sizes, int n_in,
                              void* d_out, int out_size, void* d_ws, size_t ws_size,
                              hipStream_t stream)
{
    const float* x     = (const float*)d_in[0];
    const float* w     = (const float*)d_in[1];
    const float* gamma = (const float*)d_in[2];
    const float* beta  = (const float*)d_in[3];
    float* out = (float*)d_out;
    char* ws = (char*)d_ws;

    signed char* wq       = (signed char*)(ws + WQ_OFF);
    int*         stats    = (int*)(ws + STATS_OFF);
    float*       partials = (float*)(ws + PART_OFF);
    int*         bar      = (int*)(ws + BAR_OFF);

    k_maxabs<<<dim3(64), dim3(256), 0, stream>>>(w, partials, stats, bar);
    k_wquant<<<dim3(64), dim3(256), 0, stream>>>(w, partials, wq);

    if (ws_size >= WS_MIN) {
        k_fused<<<dim3(256), dim3(1024), 0, stream>>>(x, wq, partials, stats, bar,
                                                      gamma, beta, out);
    } else {
        // fallback: old proven 4-kernel pipeline
        if (ws_size >= WS_SBUF_NEEDED) {
            signed char* sbuf = (signed char*)(ws + SBUF_OFF);
            k_gemm<signed char><<<dim3(1024), dim3(512), 0, stream>>>(x, wq, sbuf, stats);
            k_out<signed char><<<dim3(4096), dim3(256), 0, stream>>>(sbuf, stats, partials,
                                                                     gamma, beta, out);
        } else {
            k_gemm<float><<<dim3(1024), dim3(512), 0, stream>>>(x, wq, out, stats);
            k_out<float><<<dim3(4096), dim3(256), 0, stream>>>(out, stats, partials,
                                                               gamma, beta, out);
        }
    }
}

// Round 9
// 131.265 us; speedup vs baseline: 1.2131x; 1.1822x over previous
//
#include <hip/hip_runtime.h>
#include <cstdint>
#include <cstddef>

typedef int   v4i __attribute__((ext_vector_type(4)));
typedef float v4f __attribute__((ext_vector_type(4)));

static constexpr int NREP = 8;    // stats replica count (atomic contention spreading)

// ---------------- workspace layout (bytes) ----------------
static constexpr size_t WQ_OFF    = 0;                        // 65536 int8 weights
static constexpr size_t STATS_OFF = 65536;                    // NREP*512 int32 = 16384
static constexpr size_t PART_OFF  = STATS_OFF + NREP*512*4;   // 64 floats
static constexpr size_t SBUF_OFF  = 131072 + 2048;            // 16 MiB s-values (dword grid)
static constexpr size_t WS_NEEDED = SBUF_OFF + (size_t)65536 * 256;

// exact round-half-even of p/1792 for |p| <= 13440 (1792 = 7*256)
__device__ __forceinline__ int rhe1792(int p) {
    unsigned u = (unsigned)(p + 17024);      // (p+896) + 9*1792, u in [3584,30464]
    unsigned v = u >> 8;                     // floor(u/256), in [14,119]
    unsigned d = (v * 147u) >> 10;           // floor(v/7), exact for v<=119
    int q = (int)d - 9;                      // round-half-up(p/1792)
    unsigned tie = (unsigned)(((u & 255u) | (v - 7u * d)) == 0u);
    q -= (int)(tie & ((unsigned)q & 1u));    // half-even: ties round to even
    return q;
}

// ---------------- k1: per-block max|w| partials + zero stats ----------------
__global__ void k_maxabs(const float* __restrict__ w, float* __restrict__ partials,
                         int* __restrict__ stats) {
    __shared__ float wmax[4];
    int idx = blockIdx.x * 256 + threadIdx.x;     // 64 blocks * 256 = 16384 float4
    float4 f = ((const float4*)w)[idx];
    float m = fmaxf(fmaxf(fabsf(f.x), fabsf(f.y)), fmaxf(fabsf(f.z), fabsf(f.w)));
    #pragma unroll
    for (int s = 32; s > 0; s >>= 1) m = fmaxf(m, __shfl_xor(m, s, 64));
    if ((threadIdx.x & 63) == 0) wmax[threadIdx.x >> 6] = m;
    if (idx < NREP * 512) stats[idx] = 0;         // zero replicas
    __syncthreads();
    if (threadIdx.x == 0)
        partials[blockIdx.x] = fmaxf(fmaxf(wmax[0], wmax[1]), fmaxf(wmax[2], wmax[3]));
}

// wave-redundant reduce of the 64 partials (L2-hot) -> global max|w|
__device__ __forceinline__ float reduce_partials(const float* __restrict__ partials, int tid) {
    float p = partials[tid & 63];
    #pragma unroll
    for (int s = 32; s > 0; s >>= 1) p = fmaxf(p, __shfl_xor(p, s, 64));
    return p;
}

// ---------------- k2: quantize weights to int8 ----------------
__global__ void k_wquant(const float* __restrict__ w, const float* __restrict__ partials,
                         signed char* __restrict__ wq) {
    int idx = blockIdx.x * 256 + threadIdx.x;
    float scale = reduce_partials(partials, threadIdx.x) / 7.0f;  // scale_w (f32 div, as ref)
    float4 f = ((const float4*)w)[idx];
    int q0 = (int)rintf(fminf(fmaxf(f.x / scale, -7.f), 7.f));
    int q1 = (int)rintf(fminf(fmaxf(f.y / scale, -7.f), 7.f));
    int q2 = (int)rintf(fminf(fmaxf(f.z / scale, -7.f), 7.f));
    int q3 = (int)rintf(fminf(fmaxf(f.w / scale, -7.f), 7.f));
    ((int*)wq)[idx] = (q0 & 255) | ((q1 & 255) << 8) | ((q2 & 255) << 16) | ((q3 & 255) << 24);
}

// ---------------- k3: int8 MFMA GEMM + per-tile psum quant + stats ----------------
// 1024 blocks x 512 threads (8 waves), 64 batch rows/block, wf[2][4] per wave.
// ROUND-9 CHANGE vs the 132us baseline: __launch_bounds__(512,1) instead of
// (512,4). Fused-kernel ledger (rounds 1-8) showed the 2nd arg acts as a hard
// VGPR clamp (4 -> 64 regs) while this body's peak demand is ~85-90 (wf 32 +
// staging 16-32 + a/acc 24 + addressing) -> the baseline k_gemm was paying a
// hidden per-thread scratch spill. (512,1) lets the allocator pick ~88 (round-6
// precedent: no spill), still ~2 blocks/CU by VGPR. Staging split into 2 passes
// of 4 float4 (peak ~70 regs, identical per-element numerics/order per f4).
// ST=signed char: s stored as a DWORD GRID sbuf[rowgroup][col] (byte e of dword
// = row 4*rg+e): one dword store replaces 4 scattered byte stores.
template <typename ST>
__global__ __launch_bounds__(512, 1) void k_gemm(
    const float* __restrict__ x, const signed char* __restrict__ wq,
    ST* __restrict__ sbuf, int* __restrict__ stats)
{
    __shared__ __align__(16) signed char ldsx[64 * 272];   // 64 rows x 256 k (+16B pad/row)
    const int tid  = threadIdx.x;
    const int lane = tid & 63;
    const int wv   = tid >> 6;            // 0..7
    const int obase = wv * 32;            // 32 channels per wave
    const int lr = lane & 15, quad = lane >> 4;
    const size_t rb0 = (size_t)blockIdx.x * 64;

    // ---- weight fragments (L2-hot): B-operand layout n=lane&15, k=quad*16+i ----
    v4i wf[2][4];
    #pragma unroll
    for (int ot = 0; ot < 2; ++ot)
        #pragma unroll
        for (int kt = 0; kt < 4; ++kt)
            wf[ot][kt] = *(const v4i*)(wq + (size_t)(obase + ot * 16 + lr) * 256 + kt * 64 + quad * 16);

    // ---- stage x -> quantize -> LDS, 2 passes of 4 float4/thread ----
    const v4f* xb = (const v4f*)(x + rb0 * 256);
    #pragma unroll
    for (int p = 0; p < 2; ++p) {
        v4f f[4];
        #pragma unroll
        for (int j = 0; j < 4; ++j)
            f[j] = xb[p * 2048 + j * 512 + tid];
        #pragma unroll
        for (int j = 0; j < 4; ++j) {
            int idx = p * 2048 + j * 512 + tid;   // float4 flat index (0..4095)
            int row = idx >> 6, c = idx & 63;     // 64 float4 per row
            int b0 = (int)rintf(fminf(fmaxf(f[j][0], 0.f), 1.f) * 15.f);
            int b1 = (int)rintf(fminf(fmaxf(f[j][1], 0.f), 1.f) * 15.f);
            int b2 = (int)rintf(fminf(fmaxf(f[j][2], 0.f), 1.f) * 15.f);
            int b3 = (int)rintf(fminf(fmaxf(f[j][3], 0.f), 1.f) * 15.f);
            *(int*)(ldsx + row * 272 + c * 4) = b0 | (b1 << 8) | (b2 << 16) | (b3 << 24);
        }
    }
    __syncthreads();   // the ONLY barrier

    int ssum[2] = {0, 0};
    int ssq[2]  = {0, 0};

    #pragma unroll
    for (int t = 0; t < 4; ++t) {
        v4i a[4];
        #pragma unroll
        for (int kt = 0; kt < 4; ++kt)
            a[kt] = *(const v4i*)(ldsx + (t * 16 + lr) * 272 + kt * 64 + quad * 16);
        #pragma unroll
        for (int ot = 0; ot < 2; ++ot) {
            v4i acc0 = {0, 0, 0, 0}, acc1 = {0, 0, 0, 0};
            acc0 = __builtin_amdgcn_mfma_i32_16x16x64_i8(a[0], wf[ot][0], acc0, 0, 0, 0);
            acc0 = __builtin_amdgcn_mfma_i32_16x16x64_i8(a[1], wf[ot][1], acc0, 0, 0, 0);
            acc1 = __builtin_amdgcn_mfma_i32_16x16x64_i8(a[2], wf[ot][2], acc1, 0, 0, 0);
            acc1 = __builtin_amdgcn_mfma_i32_16x16x64_i8(a[3], wf[ot][3], acc1, 0, 0, 0);
            const int ocol = obase + ot * 16 + lr;
            if constexpr (sizeof(ST) == 1) {
                // vertical pack: byte e = row quad*4+e (rowgroup rg), col ocol
                unsigned pack = 0;
                #pragma unroll
                for (int e = 0; e < 4; ++e) {
                    int s = rhe1792(acc0[e]) + rhe1792(acc1[e]);   // exact, in [-16,16]
                    ssum[ot] += s;
                    ssq[ot]  += s * s;
                    pack |= (unsigned)(s & 255) << (8 * e);
                }
                const size_t rg = (size_t)blockIdx.x * 16 + t * 4 + quad;
                ((unsigned*)sbuf)[rg * 256 + ocol] = pack;
            } else {
                ST* sp = sbuf + (rb0 + (size_t)t * 16 + quad * 4) * 256 + ocol;
                #pragma unroll
                for (int e = 0; e < 4; ++e) {
                    int s = rhe1792(acc0[e]) + rhe1792(acc1[e]);
                    ssum[ot] += s;
                    ssq[ot]  += s * s;
                    sp[(size_t)e * 256] = (ST)s;
                }
            }
        }
    }
    // ---- per-channel stats into replica buffer (plain relaxed device atomics) ----
    int* st = stats + (blockIdx.x & (NREP - 1)) * 512;
    #pragma unroll
    for (int ot = 0; ot < 2; ++ot) {
        int v = ssum[ot], u = ssq[ot];
        v += __shfl_xor(v, 16, 64); v += __shfl_xor(v, 32, 64);
        u += __shfl_xor(u, 16, 64); u += __shfl_xor(u, 32, 64);
        if (quad == 0) {
            atomicAdd(&st[obase + ot * 16 + lr], v);
            atomicAdd(&st[256 + obase + ot * 16 + lr], u);
        }
    }
}

// ---------------- k4: epilogue — BN affine (computed in-block) + clipped-ReLU ----
// 4096 blocks x 256 threads. Per-block redundant BN-affine from exact integer
// stats (bit-identical op order), then: thread t reads ONE dwordx4 (16 B contig,
// 1 KB/wave) = cols 4(t&63)..+3 of rowgroup 4d+(t>>6); extracts 16 signed bytes;
// writes 4 fully-coalesced float4 row segments (1 KB/wave each). Swizzle d keeps
// (d>>2)%8 == b%8 so reads hit the writer XCD's L2.
template <typename LT>
__global__ __launch_bounds__(256) void k_out(const LT* sbuf, const int* __restrict__ stats,
                                             const float* __restrict__ partials,
                                             const float* __restrict__ gamma,
                                             const float* __restrict__ beta,
                                             float* out)
{
    __shared__ float2 ab[256];
    const int tid = threadIdx.x;
    {
        int o = tid;
        int s = 0, q = 0;
        #pragma unroll
        for (int rr = 0; rr < NREP; ++rr) {
            s += stats[rr * 512 + o];
            q += stats[rr * 512 + 256 + o];
        }
        float scale_w = reduce_partials(partials, o) / 7.0f;
        float t = scale_w / 15.0f;                 // ref: scale_w / qmax_a in f32
        double Cs = 1792.0 * (double)t;            // acc = s * Cs
        const double N = 65536.0;
        double mean_s = (double)s / N;
        double var_s  = (double)q / N - mean_s * mean_s;
        double var    = Cs * Cs * var_s;
        double inv    = 1.0 / sqrt(var + 1e-5);
        double A = Cs * inv * (double)gamma[o];
        double B = (double)beta[o] - Cs * mean_s * inv * (double)gamma[o];
        ab[o] = make_float2((float)A, (float)B);
    }
    __syncthreads();

    const int b = blockIdx.x;
    const int d = ((b & 7) << 2) | ((b >> 3) & 3) | (b & ~31);   // XCD-aligned bijection
    const int ci = tid & 63;           // colgroup index (4 cols)
    const int c0 = ci * 4;
    const float2 p0 = ab[c0], p1 = ab[c0 + 1], p2 = ab[c0 + 2], p3 = ab[c0 + 3];
    const float inv15 = 0.066666666666666666f;

    if constexpr (sizeof(LT) == 1) {
        const int rg = d * 4 + (tid >> 6);         // global rowgroup (4 rows)
        v4i V = ((const v4i*)sbuf)[(size_t)rg * 64 + ci];   // cols c0..c0+3, rows 4rg..4rg+3
        #pragma unroll
        for (int j = 0; j < 4; ++j) {
            float v0 = (float)((V[0] << (24 - 8 * j)) >> 24);
            float v1 = (float)((V[1] << (24 - 8 * j)) >> 24);
            float v2 = (float)((V[2] << (24 - 8 * j)) >> 24);
            float v3 = (float)((V[3] << (24 - 8 * j)) >> 24);
            float y0 = rintf(fminf(fmaxf(v0 * p0.x + p0.y, 0.f), 1.f) * 15.f);
            float y1 = rintf(fminf(fmaxf(v1 * p1.x + p1.y, 0.f), 1.f) * 15.f);
            float y2 = rintf(fminf(fmaxf(v2 * p2.x + p2.y, 0.f), 1.f) * 15.f);
            float y3 = rintf(fminf(fmaxf(v3 * p3.x + p3.y, 0.f), 1.f) * 15.f);
            v4f o = { y0 * inv15, y1 * inv15, y2 * inv15, y3 * inv15 };
            __builtin_nontemporal_store(o, (v4f*)out + (size_t)(4 * rg + j) * 64 + ci);
        }
    } else {
        // fallback: fp32 s row-major in d_out, finish in place (same-thread indices)
        const size_t base = (size_t)d * 1024 + tid;
        #pragma unroll
        for (int j = 0; j < 4; ++j) {
            const size_t F4 = base + (size_t)j * 256;
            v4f fl = ((const v4f*)sbuf)[F4];
            const int oo = (tid * 4) & 255;
            float2 q0 = ab[oo], q1 = ab[oo + 1], q2 = ab[oo + 2], q3 = ab[oo + 3];
            float y0 = rintf(fminf(fmaxf(fl[0] * q0.x + q0.y, 0.f), 1.f) * 15.f);
            float y1 = rintf(fminf(fmaxf(fl[1] * q1.x + q1.y, 0.f), 1.f) * 15.f);
            float y2 = rintf(fminf(fmaxf(fl[2] * q2.x + q2.y, 0.f), 1.f) * 15.f);
            float y3 = rintf(fminf(fmaxf(fl[3] * q3.x + q3.y, 0.f), 1.f) * 15.f);
            v4f o = { y0 * inv15, y1 * inv15, y2 * inv15, y3 * inv15 };
            __builtin_nontemporal_store(o, (v4f*)out + F4);
        }
    }
}

// ---------------- launch ----------------
extern "C" void kernel_launch(void* const* d_in, const int* in_sizes, int n_in,
                              void* d_out, int out_size, void* d_ws, size_t ws_size,
                              hipStream_t stream)
{
    const float* x     = (const float*)d_in[0];
    const float* w     = (const float*)d_in[1];
    const float* gamma = (const float*)d_in[2];
    const float* beta  = (const float*)d_in[3];
    float* out = (float*)d_out;
    char* ws = (char*)d_ws;

    signed char* wq       = (signed char*)(ws + WQ_OFF);
    int*         stats    = (int*)(ws + STATS_OFF);
    float*       partials = (float*)(ws + PART_OFF);

    k_maxabs<<<dim3(64), dim3(256), 0, stream>>>(w, partials, stats);
    k_wquant<<<dim3(64), dim3(256), 0, stream>>>(w, partials, wq);

    if (ws_size >= WS_NEEDED) {
        signed char* sbuf = (signed char*)(ws + SBUF_OFF);
        k_gemm<signed char><<<dim3(1024), dim3(512), 0, stream>>>(x, wq, sbuf, stats);
        k_out<signed char><<<dim3(4096), dim3(256), 0, stream>>>(sbuf, stats, partials,
                                                                 gamma, beta, out);
    } else {
        // fallback: stage s as fp32 in d_out, finish in place (same-thread indices)
        k_gemm<float><<<dim3(1024), dim3(512), 0, stream>>>(x, wq, out, stats);
        k_out<float><<<dim3(4096), dim3(256), 0, stream>>>(out, stats, partials,
                                                           gamma, beta, out);
    }
}